// Round 1
// baseline (6346.512 us; speedup 1.0000x reference)
//
#include <hip/hip_runtime.h>

#define B_   8192
#define K_   5
#define D_   128
#define QD_  129
#define KD_  1285
#define SQ_  132      // padded row stride for 129-wide matrices
#define BK_  40960    // B_*K_

// ---------------------------------------------------------------------------
// Gather for the A operand (fuses the concat/reshape ops of the reference)
// GM=0: kv rows   A[n][c], c<1285: j=c/257, r=c%257 -> emb/ef/td at (n*5+j)
// GM=1: q rows    A[n][c], c<129:  c<128 -> emb[n*128+c], c==128 -> td[n] (or 0)
// GM=2: plain     A[n][c] = g0[n*astride + c]
// GM=3: concat    A[n][c], c<257:  c<129 -> g0[n*132+c], else g1[n*128+c-129]
// ---------------------------------------------------------------------------
template<int GM>
__device__ __forceinline__ float gatherA(int n, int c,
    const float* __restrict__ g0, const float* __restrict__ g1,
    const float* __restrict__ g2, int astride)
{
  if constexpr (GM == 0) {
    int j = c / 257;
    int r = c - j * 257;
    int base = (n * 5 + j) << 7;   // *128
    if (r < 128) return g0[base + r];
    if (r < 256) return g1[base + (r - 128)];
    return g2[n * 5 + j];
  } else if constexpr (GM == 1) {
    if (c < 128) return g0[(n << 7) + c];
    return g2 ? g2[n] : 0.f;
  } else if constexpr (GM == 2) {
    return g0[n * astride + c];
  } else {
    if (c < 129) return g0[n * SQ_ + c];
    return g1[(n << 7) + (c - 129)];
  }
}

// ---------------------------------------------------------------------------
// Generic tiled GEMM: out[n][o] = op((sum_c A[n][c]*W[o][c] + b[o]) * scale)
// TM=64 rows/block, TK=32, TN=17*TGX outs. Optionally two weight sets (kp&vp
// share one pass over A). 256 threads; thread (tx,ty) owns RPT rows x 17 outs.
// ---------------------------------------------------------------------------
template<int TGX, int GM, bool RELU, bool DUAL>
__global__ __launch_bounds__(256) void gemm_k(
    int C, int astride,
    const float* __restrict__ g0, const float* __restrict__ g1, const float* __restrict__ g2,
    const float* __restrict__ W0, const float* __restrict__ b0, float* __restrict__ out0, int ost0, int N0,
    const float* __restrict__ W1, const float* __restrict__ b1, float* __restrict__ out1, int ost1, int N1,
    float scale)
{
  constexpr int TN  = 17 * TGX;
  constexpr int RPT = TGX / 4;          // 4 rows (TGX=16) or 2 rows (TGX=8)
  __shared__ float As[32][68];          // [kk][row]
  __shared__ float Ws[32][TN];          // [kk][o]
  const int t  = threadIdx.x;
  const int n0 = blockIdx.x * 64;
  const int tx = t % TGX, ty = t / TGX;
  const int o0 = tx * 17, r0 = ty * RPT;

  float acc[RPT][17];
#pragma unroll
  for (int ri = 0; ri < RPT; ++ri)
#pragma unroll
    for (int oi = 0; oi < 17; ++oi) acc[ri][oi] = 0.f;

  const int nCh = (C + 31) >> 5;
  for (int ch = 0; ch < nCh; ++ch) {
    const int c0 = ch << 5;
    __syncthreads();
    // stage A tile (64 rows x 32 cols), transposed into LDS
    for (int e = t; e < 64 * 32; e += 256) {
      int row = e >> 5, kk = e & 31, c = c0 + kk;
      float v = 0.f;
      if (c < C) v = gatherA<GM>(n0 + row, c, g0, g1, g2, astride);
      As[kk][row] = v;
    }
    // stage W tile (TN outs x 32 cols)
    for (int e = t; e < 32 * TN; e += 256) {
      int o = e >> 5, kk = e & 31, c = c0 + kk;
      float v = 0.f;
      if (c < C) {
        if (o < N0) v = W0[o * C + c];
        else if (DUAL && (o - N0) < N1) v = W1[(o - N0) * C + c];
      }
      Ws[kk][o] = v;
    }
    __syncthreads();
    for (int kk = 0; kk < 32; ++kk) {
      float a[RPT], w[17];
#pragma unroll
      for (int ri = 0; ri < RPT; ++ri) a[ri] = As[kk][r0 + ri];
#pragma unroll
      for (int oi = 0; oi < 17; ++oi) w[oi] = Ws[kk][o0 + oi];
#pragma unroll
      for (int ri = 0; ri < RPT; ++ri)
#pragma unroll
        for (int oi = 0; oi < 17; ++oi)
          acc[ri][oi] = fmaf(a[ri], w[oi], acc[ri][oi]);
    }
  }
#pragma unroll
  for (int ri = 0; ri < RPT; ++ri) {
    const int n = n0 + r0 + ri;
#pragma unroll
    for (int oi = 0; oi < 17; ++oi) {
      const int o = o0 + oi;
      float v = acc[ri][oi];
      if (o < N0) {
        v = (v + b0[o]) * scale;
        if (RELU) v = fmaxf(v, 0.f);
        out0[n * ost0 + o] = v;
      } else if (DUAL) {
        int o2 = o - N0;
        if (o2 < N1) {
          v = (v + b1[o2]) * scale;
          if (RELU) v = fmaxf(v, 0.f);
          out1[n * ost1 + o2] = v;
        }
      }
    }
  }
}

// ---------------------------------------------------------------------------
// i=0 attention: per batch b, 5 queries x 5 keys, dim 129. One wave per b,
// 4 b's per block. Writes o0 (pre-Wo) rows [n][132] with pads zeroed.
// ---------------------------------------------------------------------------
__global__ __launch_bounds__(256) void attn0_k(
    const float* __restrict__ qp, const float* __restrict__ kp,
    const float* __restrict__ vp, float* __restrict__ o0)
{
  __shared__ float qs[4][5][SQ_], ks[4][5][SQ_], vs[4][5][SQ_];
  __shared__ float ps[4][5][8];
  const int t = threadIdx.x;
  const int bbase = blockIdx.x * 4;
  for (int idx = t; idx < 4 * 5 * SQ_; idx += 256) {
    int bl = idx / (5 * SQ_);
    int rem = idx - bl * 5 * SQ_;
    int row = rem / SQ_;
    int d = rem - row * SQ_;
    int n = (bbase + bl) * 5 + row;
    float qv = 0.f, kv = 0.f, vv = 0.f;
    if (d < QD_) { qv = qp[n * SQ_ + d]; kv = kp[n * SQ_ + d]; vv = vp[n * SQ_ + d]; }
    qs[bl][row][d] = qv; ks[bl][row][d] = kv; vs[bl][row][d] = vv;
  }
  __syncthreads();
  const int w = t >> 6, lane = t & 63;
  if (lane < 25) {
    int qq = lane / 5, kk = lane - (lane / 5) * 5;
    float s = 0.f;
    for (int c = 0; c < QD_; ++c) s += qs[w][qq][c] * ks[w][kk][c];
    ps[w][qq][kk] = s;
  }
  __syncthreads();
  if (lane < 5) {
    float m = -1e30f;
#pragma unroll
    for (int k = 0; k < 5; ++k) m = fmaxf(m, ps[w][lane][k]);
    float l = 0.f; float e[5];
#pragma unroll
    for (int k = 0; k < 5; ++k) { e[k] = __expf(ps[w][lane][k] - m); l += e[k]; }
    float inv = 1.f / l;
#pragma unroll
    for (int k = 0; k < 5; ++k) ps[w][lane][k] = e[k] * inv;
  }
  __syncthreads();
  for (int d = lane; d < SQ_; d += 64) {
#pragma unroll
    for (int qq = 0; qq < 5; ++qq) {
      float o = 0.f;
#pragma unroll
      for (int k = 0; k < 5; ++k) o += ps[w][qq][k] * vs[w][k][d];
      o0[((bbase + w) * 5 + qq) * SQ_ + d] = o;
    }
  }
}

// ---------------------------------------------------------------------------
// i=1 flash attention: 8192 queries x 8192 keys, dim 129 (scale already in qp).
// Block = 32 q-rows, streams keys 64 at a time, online softmax.
// Thread (q = t&31, g = t>>5): scores for k-group g (8 keys), accumulates
// output dims d = g*16..g*16+15 (+ d=128 on g==0).
// ---------------------------------------------------------------------------
#define FQ 32
#define FK 64
__global__ __launch_bounds__(256) void flash1_k(
    const float* __restrict__ qp, const float* __restrict__ kp,
    const float* __restrict__ vp, float* __restrict__ o1)
{
  __shared__ float qs[FQ][SQ_];
  __shared__ float ks[FK][SQ_];
  __shared__ float vs[FK][SQ_];
  __shared__ float ss[FQ][FK + 1];
  __shared__ float pmx[FQ][9], psm[FQ][9];
  __shared__ float mm[FQ], ll[FQ], cf[FQ];
  const int t = threadIdx.x;
  const int q0 = blockIdx.x * FQ;
  for (int idx = t; idx < FQ * SQ_; idx += 256) {
    int qq = idx / SQ_, d = idx - qq * SQ_;
    qs[qq][d] = (d < QD_) ? qp[(q0 + qq) * SQ_ + d] : 0.f;
  }
  if (t < FQ) { mm[t] = -1e30f; ll[t] = 0.f; }
  float acc[17];
#pragma unroll
  for (int i = 0; i < 17; ++i) acc[i] = 0.f;
  const int q = t & 31;
  const int g = t >> 5;   // 0..7

  for (int kt = 0; kt < B_; kt += FK) {
    __syncthreads();
    for (int idx = t; idx < FK * SQ_; idx += 256) {
      int k = idx / SQ_, d = idx - k * SQ_;
      bool ok = d < QD_;
      ks[k][d] = ok ? kp[(kt + k) * SQ_ + d] : 0.f;
      vs[k][d] = ok ? vp[(kt + k) * SQ_ + d] : 0.f;
    }
    __syncthreads();
    // scores: 8 keys per thread over 132 dims (pads are zero)
    float sc[8];
#pragma unroll
    for (int j = 0; j < 8; ++j) sc[j] = 0.f;
    for (int c = 0; c < SQ_; c += 4) {
#pragma unroll
      for (int u = 0; u < 4; ++u) {
        float qv = qs[q][c + u];
#pragma unroll
        for (int j = 0; j < 8; ++j) sc[j] = fmaf(qv, ks[g * 8 + j][c + u], sc[j]);
      }
    }
    float pm = sc[0];
#pragma unroll
    for (int j = 1; j < 8; ++j) pm = fmaxf(pm, sc[j]);
    pmx[q][g] = pm;
    __syncthreads();
    if (t < FQ) {
      float m = mm[t];
#pragma unroll
      for (int gg = 0; gg < 8; ++gg) m = fmaxf(m, pmx[t][gg]);
      cf[t] = __expf(mm[t] - m);
      mm[t] = m;
    }
    __syncthreads();
    const float mnew = mm[q];
    float psum = 0.f;
#pragma unroll
    for (int j = 0; j < 8; ++j) {
      float e = __expf(sc[j] - mnew);
      ss[q][g * 8 + j] = e;
      psum += e;
    }
    psm[q][g] = psum;
    __syncthreads();
    if (t < FQ) {
      float s = 0.f;
#pragma unroll
      for (int gg = 0; gg < 8; ++gg) s += psm[t][gg];
      ll[t] = ll[t] * cf[t] + s;
    }
    const float corr = cf[q];
#pragma unroll
    for (int i = 0; i < 17; ++i) acc[i] *= corr;
    for (int k = 0; k < FK; ++k) {
      float p = ss[q][k];
#pragma unroll
      for (int i = 0; i < 16; ++i) acc[i] = fmaf(p, vs[k][g * 16 + i], acc[i]);
      if (g == 0) acc[16] = fmaf(p, vs[k][128], acc[16]);
    }
  }
  __syncthreads();
  const float linv = 1.f / ll[q];
  const int nrow = q0 + q;
#pragma unroll
  for (int i = 0; i < 16; ++i) o1[nrow * SQ_ + g * 16 + i] = acc[i] * linv;
  if (g == 0) o1[nrow * SQ_ + 128] = acc[16] * linv;
}

// ---------------------------------------------------------------------------
extern "C" void kernel_launch(void* const* d_in, const int* in_sizes, int n_in,
                              void* d_out, int out_size, void* d_ws, size_t ws_size,
                              hipStream_t stream)
{
  const float* emb0 = (const float*)d_in[0];
  const float* ef0  = (const float*)d_in[1];
  const float* td0  = (const float*)d_in[2];
  const float* emb1 = (const float*)d_in[3];
  const float* ef1  = (const float*)d_in[4];
  const float* td1  = (const float*)d_in[5];
  const float* emb2 = (const float*)d_in[6];
  const float* Wq = (const float*)d_in[7];  const float* bq = (const float*)d_in[8];
  const float* Wk = (const float*)d_in[9];  const float* bk = (const float*)d_in[10];
  const float* Wv = (const float*)d_in[11]; const float* bv = (const float*)d_in[12];
  const float* Wo = (const float*)d_in[13]; const float* bo = (const float*)d_in[14];
  const float* W1 = (const float*)d_in[15]; const float* b1 = (const float*)d_in[16];
  const float* W2 = (const float*)d_in[17]; const float* b2 = (const float*)d_in[18];
  float* out = (float*)d_out;

  float* ws  = (float*)d_ws;
  float* kp0 = ws;
  float* vp0 = kp0 + (size_t)BK_ * SQ_;
  float* qp0 = vp0 + (size_t)BK_ * SQ_;
  float* o0  = qp0 + (size_t)BK_ * SQ_;
  float* kp1 = o0  + (size_t)BK_ * SQ_;
  float* vp1 = kp1 + (size_t)B_ * SQ_;
  float* qp1 = vp1 + (size_t)B_ * SQ_;
  float* o1  = qp1 + (size_t)B_ * SQ_;
  float* a0 = kp0;   // reuse: kp0 dead after attn0
  float* h0 = qp0;   // reuse: qp0 dead after attn0
  float* a1 = kp1;   // reuse: kp1 dead after flash
  float* h1 = qp1;   // reuse: qp1 dead after flash

  const float scale = 0.08804509063256238f;  // 1/sqrt(129)

  // ---- i = 0 -------------------------------------------------------------
  // kp0,vp0 = nf0 @ {Wk,Wv}^T + {bk,bv}
  gemm_k<16, 0, false, true><<<BK_ / 64, 256, 0, stream>>>(
      KD_, 0, emb0, ef0, td0,
      Wk, bk, kp0, SQ_, QD_, Wv, bv, vp0, SQ_, QD_, 1.f);
  // qp0 = (q0 @ Wq^T + bq) * scale
  gemm_k<8, 1, false, false><<<BK_ / 64, 256, 0, stream>>>(
      QD_, 0, emb1, nullptr, td1,
      Wq, bq, qp0, SQ_, QD_, nullptr, nullptr, nullptr, 0, 0, scale);
  attn0_k<<<B_ / 4, 256, 0, stream>>>(qp0, kp0, vp0, o0);
  // a0 = o0 @ Wo^T + bo
  gemm_k<8, 2, false, false><<<BK_ / 64, 256, 0, stream>>>(
      QD_, SQ_, o0, nullptr, nullptr,
      Wo, bo, a0, SQ_, QD_, nullptr, nullptr, nullptr, 0, 0, 1.f);
  // h0 = relu(concat(a0, emb1) @ W1^T + b1)
  gemm_k<8, 3, true, false><<<BK_ / 64, 256, 0, stream>>>(
      257, 0, a0, emb1, nullptr,
      W1, b1, h0, 128, 128, nullptr, nullptr, nullptr, 0, 0, 1.f);
  // r0 = h0 @ W2^T + b2  -> d_out[0 : 40960*128]
  gemm_k<8, 2, false, false><<<BK_ / 64, 256, 0, stream>>>(
      128, 128, h0, nullptr, nullptr,
      W2, b2, out, 128, 128, nullptr, nullptr, nullptr, 0, 0, 1.f);

  // ---- i = 1 -------------------------------------------------------------
  gemm_k<16, 0, false, true><<<B_ / 64, 256, 0, stream>>>(
      KD_, 0, emb1, ef1, td1,
      Wk, bk, kp1, SQ_, QD_, Wv, bv, vp1, SQ_, QD_, 1.f);
  gemm_k<8, 1, false, false><<<B_ / 64, 256, 0, stream>>>(
      QD_, 0, emb2, nullptr, nullptr,
      Wq, bq, qp1, SQ_, QD_, nullptr, nullptr, nullptr, 0, 0, scale);
  flash1_k<<<B_ / FQ, 256, 0, stream>>>(qp1, kp1, vp1, o1);
  gemm_k<8, 2, false, false><<<B_ / 64, 256, 0, stream>>>(
      QD_, SQ_, o1, nullptr, nullptr,
      Wo, bo, a1, SQ_, QD_, nullptr, nullptr, nullptr, 0, 0, 1.f);
  gemm_k<8, 3, true, false><<<B_ / 64, 256, 0, stream>>>(
      257, 0, a1, emb2, nullptr,
      W1, b1, h1, 128, 128, nullptr, nullptr, nullptr, 0, 0, 1.f);
  gemm_k<8, 2, false, false><<<B_ / 64, 256, 0, stream>>>(
      128, 128, h1, nullptr, nullptr,
      W2, b2, out + (size_t)BK_ * D_, 128, 128, nullptr, nullptr, nullptr, 0, 0, 1.f);
}

// Round 2
// 2478.222 us; speedup vs baseline: 2.5609x; 2.5609x over previous
//
#include <hip/hip_runtime.h>

#define B_   8192
#define K_   5
#define D_   128
#define QD_  129
#define KD_  1285
#define SQ_  132      // padded fp32 row stride for 129-wide matrices
#define BK_  40960    // B_*K_
#define QPAD 160      // bf16 k-dim padding for MFMA (5 x 32)
#define VPAD 144      // bf16 out-dim padding (9 x 16)

typedef unsigned short u16;
typedef unsigned int   u32;
typedef __attribute__((ext_vector_type(8))) short bf8_t;
typedef __attribute__((ext_vector_type(4))) float f4_t;

#define MFMA16(a, b, c) __builtin_amdgcn_mfma_f32_16x16x32_bf16(a, b, c, 0, 0, 0)

__device__ __forceinline__ u16 f2bf(float x) {
  u32 u = __float_as_uint(x);
  u = (u + 0x7fffu + ((u >> 16) & 1u)) >> 16;
  return (u16)u;
}
__device__ __forceinline__ u32 pack2(float a, float b) {
  return (u32)f2bf(a) | ((u32)f2bf(b) << 16);
}

// ---------------------------------------------------------------------------
// Gather for the A operand (fuses the concat/reshape ops of the reference)
// ---------------------------------------------------------------------------
template<int GM>
__device__ __forceinline__ float gatherA(int n, int c,
    const float* __restrict__ g0, const float* __restrict__ g1,
    const float* __restrict__ g2, int astride)
{
  if constexpr (GM == 0) {
    int j = c / 257;
    int r = c - j * 257;
    int base = (n * 5 + j) << 7;   // *128
    if (r < 128) return g0[base + r];
    if (r < 256) return g1[base + (r - 128)];
    return g2[n * 5 + j];
  } else if constexpr (GM == 1) {
    if (c < 128) return g0[(n << 7) + c];
    return g2 ? g2[n] : 0.f;
  } else if constexpr (GM == 2) {
    return g0[n * astride + c];
  } else {
    if (c < 129) return g0[n * SQ_ + c];
    return g1[(n << 7) + (c - 129)];
  }
}

// ---------------------------------------------------------------------------
// fp32 tiled GEMM for the small projections (qp, Wo, W1, W2).
// OM: 0 = f32 row-major, 1 = bf16 row-major, 2 = bf16 transposed.
// ---------------------------------------------------------------------------
template<int TGX, int GM, bool RELU, bool DUAL, int OM0, int OM1>
__global__ __launch_bounds__(256) void gemm_k(
    int C, int astride,
    const float* __restrict__ g0, const float* __restrict__ g1, const float* __restrict__ g2,
    const float* __restrict__ W0, const float* __restrict__ b0, void* __restrict__ out0, int ost0, int N0,
    const float* __restrict__ W1, const float* __restrict__ b1, void* __restrict__ out1, int ost1, int N1,
    float scale)
{
  constexpr int TN  = 17 * TGX;
  constexpr int RPT = TGX / 4;
  __shared__ float As[32][68];
  __shared__ float Ws[32][TN];
  const int t  = threadIdx.x;
  const int n0 = blockIdx.x * 64;
  const int tx = t % TGX, ty = t / TGX;
  const int o0 = tx * 17, r0 = ty * RPT;

  float acc[RPT][17];
#pragma unroll
  for (int ri = 0; ri < RPT; ++ri)
#pragma unroll
    for (int oi = 0; oi < 17; ++oi) acc[ri][oi] = 0.f;

  const int nCh = (C + 31) >> 5;
  for (int ch = 0; ch < nCh; ++ch) {
    const int c0 = ch << 5;
    __syncthreads();
    for (int e = t; e < 64 * 32; e += 256) {
      int row = e >> 5, kk = e & 31, c = c0 + kk;
      float v = 0.f;
      if (c < C) v = gatherA<GM>(n0 + row, c, g0, g1, g2, astride);
      As[kk][row] = v;
    }
    for (int e = t; e < 32 * TN; e += 256) {
      int o = e >> 5, kk = e & 31, c = c0 + kk;
      float v = 0.f;
      if (c < C) {
        if (o < N0) v = W0[o * C + c];
        else if (DUAL && (o - N0) < N1) v = W1[(o - N0) * C + c];
      }
      Ws[kk][o] = v;
    }
    __syncthreads();
    for (int kk = 0; kk < 32; ++kk) {
      float a[RPT], w[17];
#pragma unroll
      for (int ri = 0; ri < RPT; ++ri) a[ri] = As[kk][r0 + ri];
#pragma unroll
      for (int oi = 0; oi < 17; ++oi) w[oi] = Ws[kk][o0 + oi];
#pragma unroll
      for (int ri = 0; ri < RPT; ++ri)
#pragma unroll
        for (int oi = 0; oi < 17; ++oi)
          acc[ri][oi] = fmaf(a[ri], w[oi], acc[ri][oi]);
    }
  }
#pragma unroll
  for (int ri = 0; ri < RPT; ++ri) {
    const int n = n0 + r0 + ri;
#pragma unroll
    for (int oi = 0; oi < 17; ++oi) {
      const int o = o0 + oi;
      float v = acc[ri][oi];
      if (o < N0) {
        v = (v + b0[o]) * scale;
        if (RELU) v = fmaxf(v, 0.f);
        if (OM0 == 0)      ((float*)out0)[n * ost0 + o] = v;
        else if (OM0 == 1) ((u16*)out0)[n * ost0 + o] = f2bf(v);
        else               ((u16*)out0)[(size_t)o * ost0 + n] = f2bf(v);
      } else if (DUAL) {
        int o2 = o - N0;
        if (o2 < N1) {
          v = (v + b1[o2]) * scale;
          if (RELU) v = fmaxf(v, 0.f);
          if (OM1 == 0)      ((float*)out1)[n * ost1 + o2] = v;
          else if (OM1 == 1) ((u16*)out1)[n * ost1 + o2] = f2bf(v);
          else               ((u16*)out1)[(size_t)o2 * ost1 + n] = f2bf(v);
        }
      }
    }
  }
}

// ---------------------------------------------------------------------------
// MFMA bf16 projection: [kp;vp] = gather(nf) @ [Wk;Wv]^T + [bk;bv]
// BM=64, BN=288 (258 real), K padded 1285->1312 (41 steps of 32).
// 4 waves as 2x2: wave (wr,wc): rows wr*32 (2 frags of 16), cols wc*144 (9 ct).
// ---------------------------------------------------------------------------
template<int GM, int OM0, int OM1>
__global__ __launch_bounds__(256) void projmm_k(
    const float* __restrict__ g0, const float* __restrict__ g1, const float* __restrict__ g2,
    const float* __restrict__ W0, const float* __restrict__ b0, void* __restrict__ out0, int ost0,
    const float* __restrict__ W1, const float* __restrict__ b1, void* __restrict__ out1, int ost1)
{
  __shared__ u16 As[64 * 40];    // [row][k] stride 40 (2-way banks)
  __shared__ u16 Ws_[288 * 40];  // [outcol][k]
  const int t = threadIdx.x;
  const int n0 = blockIdx.x * 64;
  const int lane = t & 63, w = t >> 6;
  const int lrow = lane & 15, lk = lane >> 4;
  const int wr = w & 1, wc = w >> 1;

  f4_t acc0[9], acc1[9];
#pragma unroll
  for (int ct = 0; ct < 9; ++ct) {
    acc0[ct] = (f4_t){0.f, 0.f, 0.f, 0.f};
    acc1[ct] = (f4_t){0.f, 0.f, 0.f, 0.f};
  }

  for (int kst = 0; kst < 41; ++kst) {
    const int c0 = kst * 32;
    __syncthreads();
    // stage A: 64 rows x 16 dword-pairs
    for (int e = t; e < 1024; e += 256) {
      int row = e >> 4, cp = e & 15;
      int c = c0 + cp * 2;
      float f0 = (c     < KD_) ? gatherA<GM>(n0 + row, c,     g0, g1, g2, 0) : 0.f;
      float f1 = (c + 1 < KD_) ? gatherA<GM>(n0 + row, c + 1, g0, g1, g2, 0) : 0.f;
      *(u32*)&As[row * 40 + cp * 2] = pack2(f0, f1);
    }
    // stage W: 288 cols x 16 dword-pairs (fp32 -> bf16)
    for (int e = t; e < 4608; e += 256) {
      int col = e >> 4, cp = e & 15;
      int c = c0 + cp * 2;
      float f0 = 0.f, f1 = 0.f;
      if (col < 129) {
        if (c     < KD_) f0 = W0[col * KD_ + c];
        if (c + 1 < KD_) f1 = W0[col * KD_ + c + 1];
      } else if (col < 258) {
        int o = col - 129;
        if (c     < KD_) f0 = W1[o * KD_ + c];
        if (c + 1 < KD_) f1 = W1[o * KD_ + c + 1];
      }
      *(u32*)&Ws_[col * 40 + cp * 2] = pack2(f0, f1);
    }
    __syncthreads();
    bf8_t af0 = *(const bf8_t*)&As[(wr * 32 +      lrow) * 40 + lk * 8];
    bf8_t af1 = *(const bf8_t*)&As[(wr * 32 + 16 + lrow) * 40 + lk * 8];
#pragma unroll
    for (int ct = 0; ct < 9; ++ct) {
      bf8_t bf = *(const bf8_t*)&Ws_[(wc * 144 + ct * 16 + lrow) * 40 + lk * 8];
      acc0[ct] = MFMA16(af0, bf, acc0[ct]);
      acc1[ct] = MFMA16(af1, bf, acc1[ct]);
    }
  }

#pragma unroll
  for (int ct = 0; ct < 9; ++ct) {
    const int col = wc * 144 + ct * 16 + lrow;
#pragma unroll
    for (int rf = 0; rf < 2; ++rf) {
#pragma unroll
      for (int r = 0; r < 4; ++r) {
        const int n = n0 + wr * 32 + rf * 16 + lk * 4 + r;
        float v = (rf == 0) ? acc0[ct][r] : acc1[ct][r];
        if (col < 129) {
          v += b0[col];
          if (OM0 == 0)      ((float*)out0)[(size_t)n * ost0 + col] = v;
          else if (OM0 == 1) ((u16*)out0)[(size_t)n * ost0 + col] = f2bf(v);
          else               ((u16*)out0)[(size_t)col * ost0 + n] = f2bf(v);
        } else if (col < 258) {
          int o = col - 129;
          v += b1[o];
          if (OM1 == 0)      ((float*)out1)[(size_t)n * ost1 + o] = v;
          else if (OM1 == 1) ((u16*)out1)[(size_t)n * ost1 + o] = f2bf(v);
          else               ((u16*)out1)[(size_t)o * ost1 + n] = f2bf(v);
        }
      }
    }
  }
}

// ---------------------------------------------------------------------------
// i=0 attention: per batch b, 5 queries x 5 keys, dim 129 (unchanged).
// ---------------------------------------------------------------------------
__global__ __launch_bounds__(256) void attn0_k(
    const float* __restrict__ qp, const float* __restrict__ kp,
    const float* __restrict__ vp, float* __restrict__ o0)
{
  __shared__ float qs[4][5][SQ_], ks[4][5][SQ_], vs[4][5][SQ_];
  __shared__ float ps[4][5][8];
  const int t = threadIdx.x;
  const int bbase = blockIdx.x * 4;
  for (int idx = t; idx < 4 * 5 * SQ_; idx += 256) {
    int bl = idx / (5 * SQ_);
    int rem = idx - bl * 5 * SQ_;
    int row = rem / SQ_;
    int d = rem - row * SQ_;
    int n = (bbase + bl) * 5 + row;
    float qv = 0.f, kv = 0.f, vv = 0.f;
    if (d < QD_) { qv = qp[n * SQ_ + d]; kv = kp[n * SQ_ + d]; vv = vp[n * SQ_ + d]; }
    qs[bl][row][d] = qv; ks[bl][row][d] = kv; vs[bl][row][d] = vv;
  }
  __syncthreads();
  const int w = t >> 6, lane = t & 63;
  if (lane < 25) {
    int qq = lane / 5, kk = lane - (lane / 5) * 5;
    float s = 0.f;
    for (int c = 0; c < QD_; ++c) s += qs[w][qq][c] * ks[w][kk][c];
    ps[w][qq][kk] = s;
  }
  __syncthreads();
  if (lane < 5) {
    float m = -1e30f;
#pragma unroll
    for (int k = 0; k < 5; ++k) m = fmaxf(m, ps[w][lane][k]);
    float l = 0.f; float e[5];
#pragma unroll
    for (int k = 0; k < 5; ++k) { e[k] = __expf(ps[w][lane][k] - m); l += e[k]; }
    float inv = 1.f / l;
#pragma unroll
    for (int k = 0; k < 5; ++k) ps[w][lane][k] = e[k] * inv;
  }
  __syncthreads();
  for (int d = lane; d < SQ_; d += 64) {
#pragma unroll
    for (int qq = 0; qq < 5; ++qq) {
      float o = 0.f;
#pragma unroll
      for (int k = 0; k < 5; ++k) o += ps[w][qq][k] * vs[w][k][d];
      o0[((bbase + w) * 5 + qq) * SQ_ + d] = o;
    }
  }
}

// ---------------------------------------------------------------------------
// i=1 MFMA flash attention. 64 q-rows/block, 4 K-splits (2048 keys each),
// 64-key tiles. 4 waves; wave w owns q-rows w*16..+16. Online softmax in
// registers via 16-lane shfl groups. Unnormalized acc + (m,l) per split.
// ---------------------------------------------------------------------------
#define KSS 168
#define VSS 72
#define PSS 72
#define NSPLIT 4
__global__ __launch_bounds__(256) void flashm_k(
    const u16* __restrict__ qp, const u16* __restrict__ kp,
    const u16* __restrict__ vpT, float* __restrict__ oacc,
    float* __restrict__ marr, float* __restrict__ larr)
{
  __shared__ u16 ks[64 * KSS];
  __shared__ u16 vsT[VPAD * VSS];
  __shared__ u16 ps[64 * PSS];
  const int t = threadIdx.x;
  const int split = blockIdx.x & (NSPLIT - 1);
  const int q0 = (blockIdx.x >> 2) * 64;
  const int w = t >> 6, lane = t & 63;
  const int lrow = lane & 15, lk = lane >> 4;

  // Q fragments (5 ksteps), one-time global load
  bf8_t qf[5];
  {
    const u16* qrow = qp + (size_t)(q0 + w * 16 + lrow) * QPAD;
#pragma unroll
    for (int kst = 0; kst < 5; ++kst)
      qf[kst] = *(const bf8_t*)(qrow + kst * 32 + lk * 8);
  }

  f4_t acc[9];
#pragma unroll
  for (int ct = 0; ct < 9; ++ct) acc[ct] = (f4_t){0.f, 0.f, 0.f, 0.f};
  float m_[4] = {-1e30f, -1e30f, -1e30f, -1e30f};
  float l_[4] = {0.f, 0.f, 0.f, 0.f};

  const int kbase = split * (B_ / NSPLIT);
  for (int tile = 0; tile < (B_ / NSPLIT) / 64; ++tile) {
    const int k0 = kbase + tile * 64;
    __syncthreads();
    for (int e = t; e < 64 * 20; e += 256) {      // K tile: 64 rows x 20 uint4
      int r = e / 20, c = e - r * 20;
      *(uint4*)&ks[r * KSS + c * 8] = *(const uint4*)(kp + (size_t)(k0 + r) * QPAD + c * 8);
    }
    for (int e = t; e < VPAD * 8; e += 256) {     // V^T tile: 144 rows x 8 uint4
      int r = e >> 3, c = e & 7;
      *(uint4*)&vsT[r * VSS + c * 8] = *(const uint4*)(vpT + (size_t)r * B_ + k0 + c * 8);
    }
    __syncthreads();

    // QK^T: 4 col-tiles x 5 ksteps
    f4_t s[4];
#pragma unroll
    for (int ct = 0; ct < 4; ++ct) s[ct] = (f4_t){0.f, 0.f, 0.f, 0.f};
#pragma unroll
    for (int kst = 0; kst < 5; ++kst) {
#pragma unroll
      for (int ct = 0; ct < 4; ++ct) {
        bf8_t b = *(const bf8_t*)&ks[(ct * 16 + lrow) * KSS + kst * 32 + lk * 8];
        s[ct] = MFMA16(qf[kst], b, s[ct]);
      }
    }

    // online softmax (rows lk*4+r, 16-lane groups share rows)
    float pm[4];
#pragma unroll
    for (int r = 0; r < 4; ++r) {
      pm[r] = fmaxf(fmaxf(s[0][r], s[1][r]), fmaxf(s[2][r], s[3][r]));
#pragma unroll
      for (int mk = 1; mk <= 8; mk <<= 1) pm[r] = fmaxf(pm[r], __shfl_xor(pm[r], mk));
    }
    float cf[4], rs[4];
#pragma unroll
    for (int r = 0; r < 4; ++r) {
      float mn = fmaxf(m_[r], pm[r]);
      cf[r] = __expf(m_[r] - mn);
      m_[r] = mn;
      rs[r] = 0.f;
    }
#pragma unroll
    for (int ct = 0; ct < 4; ++ct) {
#pragma unroll
      for (int r = 0; r < 4; ++r) {
        float p = __expf(s[ct][r] - m_[r]);
        ps[(w * 16 + lk * 4 + r) * PSS + ct * 16 + lrow] = f2bf(p);
        rs[r] += p;
      }
    }
#pragma unroll
    for (int r = 0; r < 4; ++r) {
#pragma unroll
      for (int mk = 1; mk <= 8; mk <<= 1) rs[r] += __shfl_xor(rs[r], mk);
      l_[r] = l_[r] * cf[r] + rs[r];
    }
#pragma unroll
    for (int ct = 0; ct < 9; ++ct) {
#pragma unroll
      for (int r = 0; r < 4; ++r) acc[ct][r] *= cf[r];
    }
    __syncthreads();   // ps visibility across lanes before MFMA reads

    // PV: 9 col-tiles x 2 ksteps
#pragma unroll
    for (int kst = 0; kst < 2; ++kst) {
      bf8_t a = *(const bf8_t*)&ps[(w * 16 + lrow) * PSS + kst * 32 + lk * 8];
#pragma unroll
      for (int ct = 0; ct < 9; ++ct) {
        bf8_t b = *(const bf8_t*)&vsT[(ct * 16 + lrow) * VSS + kst * 32 + lk * 8];
        acc[ct] = MFMA16(a, b, acc[ct]);
      }
    }
  }

  // store unnormalized acc + m,l
#pragma unroll
  for (int ct = 0; ct < 9; ++ct) {
    const int col = ct * 16 + lrow;
    if (col < SQ_) {
#pragma unroll
      for (int r = 0; r < 4; ++r)
        oacc[((size_t)split * B_ + q0 + w * 16 + lk * 4 + r) * SQ_ + col] = acc[ct][r];
    }
  }
  if (lrow == 0) {
#pragma unroll
    for (int r = 0; r < 4; ++r) {
      size_t i = (size_t)split * B_ + q0 + w * 16 + lk * 4 + r;
      marr[i] = m_[r];
      larr[i] = l_[r];
    }
  }
}

// ---------------------------------------------------------------------------
// combine the 4 split partials -> o1 [8192][132] fp32
// ---------------------------------------------------------------------------
__global__ __launch_bounds__(256) void combine_k(
    const float* __restrict__ oacc, const float* __restrict__ marr,
    const float* __restrict__ larr, float* __restrict__ o1)
{
  int idx = blockIdx.x * 256 + threadIdx.x;
  if (idx >= B_ * SQ_) return;
  int n = idx / SQ_, d = idx - n * SQ_;
  float m = -1e30f;
#pragma unroll
  for (int s = 0; s < NSPLIT; ++s) m = fmaxf(m, marr[s * B_ + n]);
  float l = 0.f, o = 0.f;
#pragma unroll
  for (int s = 0; s < NSPLIT; ++s) {
    float e = __expf(marr[s * B_ + n] - m);
    l += larr[s * B_ + n] * e;
    o += oacc[((size_t)s * B_ + n) * SQ_ + d] * e;
  }
  o1[idx] = o / l;
}

// ---------------------------------------------------------------------------
extern "C" void kernel_launch(void* const* d_in, const int* in_sizes, int n_in,
                              void* d_out, int out_size, void* d_ws, size_t ws_size,
                              hipStream_t stream)
{
  const float* emb0 = (const float*)d_in[0];
  const float* ef0  = (const float*)d_in[1];
  const float* td0  = (const float*)d_in[2];
  const float* emb1 = (const float*)d_in[3];
  const float* ef1  = (const float*)d_in[4];
  const float* td1  = (const float*)d_in[5];
  const float* emb2 = (const float*)d_in[6];
  const float* Wq = (const float*)d_in[7];  const float* bq = (const float*)d_in[8];
  const float* Wk = (const float*)d_in[9];  const float* bk = (const float*)d_in[10];
  const float* Wv = (const float*)d_in[11]; const float* bv = (const float*)d_in[12];
  const float* Wo = (const float*)d_in[13]; const float* bo = (const float*)d_in[14];
  const float* W1 = (const float*)d_in[15]; const float* b1 = (const float*)d_in[16];
  const float* W2 = (const float*)d_in[17]; const float* b2 = (const float*)d_in[18];
  float* out = (float*)d_out;

  char* ws = (char*)d_ws;
  // ---- i=0 buffers (fp32) ----
  float* kp0 = (float*)ws;
  float* vp0 = kp0 + (size_t)BK_ * SQ_;
  float* qp0 = vp0 + (size_t)BK_ * SQ_;
  float* o0  = qp0 + (size_t)BK_ * SQ_;
  float* a0 = kp0;   // reuse after attn0
  float* h0 = qp0;
  // ---- i=1 buffers (overlay from ws base; i=0 fully drained first) ----
  u16*   qp1b = (u16*)ws;                          // [8192][160] bf16
  u16*   kp1b = (u16*)(ws + 2621440);              // [8192][160] bf16
  u16*   vp1T = (u16*)(ws + 5242880);              // [144][8192] bf16
  float* oacc = (float*)(ws + 7602176);            // [4][8192][132]
  float* marr = (float*)(ws + 24903680);           // [4][8192]
  float* larr = (float*)(ws + 25034752);           // [4][8192]
  float* o1   = (float*)(ws + 25165824);           // [8192][132]
  float* a1   = (float*)(ws + 29491200);
  float* h1   = (float*)(ws + 33816576);

  const float scale = 0.08804509063256238f;  // 1/sqrt(129)

  // ---- i = 0 -------------------------------------------------------------
  projmm_k<0, 0, 0><<<BK_ / 64, 256, 0, stream>>>(
      emb0, ef0, td0, Wk, bk, kp0, SQ_, Wv, bv, vp0, SQ_);
  gemm_k<8, 1, false, false, 0, 0><<<BK_ / 64, 256, 0, stream>>>(
      QD_, 0, emb1, nullptr, td1,
      Wq, bq, qp0, SQ_, QD_, nullptr, nullptr, nullptr, 0, 0, scale);
  attn0_k<<<B_ / 4, 256, 0, stream>>>(qp0, kp0, vp0, o0);
  gemm_k<8, 2, false, false, 0, 0><<<BK_ / 64, 256, 0, stream>>>(
      QD_, SQ_, o0, nullptr, nullptr,
      Wo, bo, a0, SQ_, QD_, nullptr, nullptr, nullptr, 0, 0, 1.f);
  gemm_k<8, 3, true, false, 0, 0><<<BK_ / 64, 256, 0, stream>>>(
      257, 0, a0, emb1, nullptr,
      W1, b1, h0, 128, 128, nullptr, nullptr, nullptr, 0, 0, 1.f);
  gemm_k<8, 2, false, false, 0, 0><<<BK_ / 64, 256, 0, stream>>>(
      128, 128, h0, nullptr, nullptr,
      W2, b2, out, 128, 128, nullptr, nullptr, nullptr, 0, 0, 1.f);

  // ---- i = 1 -------------------------------------------------------------
  hipMemsetAsync(qp1b, 0, 2621440, stream);
  hipMemsetAsync(kp1b, 0, 2621440, stream);
  hipMemsetAsync(vp1T, 0, 2359296, stream);
  projmm_k<0, 1, 2><<<B_ / 64, 256, 0, stream>>>(
      emb1, ef1, td1, Wk, bk, kp1b, QPAD, Wv, bv, vp1T, B_);
  gemm_k<8, 1, false, false, 1, 0><<<B_ / 64, 256, 0, stream>>>(
      QD_, 0, emb2, nullptr, nullptr,
      Wq, bq, qp1b, QPAD, QD_, nullptr, nullptr, nullptr, 0, 0, scale);
  flashm_k<<<(B_ / 64) * NSPLIT, 256, 0, stream>>>(qp1b, kp1b, vp1T, oacc, marr, larr);
  combine_k<<<(B_ * SQ_ + 255) / 256, 256, 0, stream>>>(oacc, marr, larr, o1);
  gemm_k<8, 2, false, false, 0, 0><<<B_ / 64, 256, 0, stream>>>(
      QD_, SQ_, o1, nullptr, nullptr,
      Wo, bo, a1, SQ_, QD_, nullptr, nullptr, nullptr, 0, 0, 1.f);
  gemm_k<8, 3, true, false, 0, 0><<<B_ / 64, 256, 0, stream>>>(
      257, 0, a1, emb2, nullptr,
      W1, b1, h1, 128, 128, nullptr, nullptr, nullptr, 0, 0, 1.f);
  gemm_k<8, 2, false, false, 0, 0><<<B_ / 64, 256, 0, stream>>>(
      128, 128, h1, nullptr, nullptr,
      W2, b2, out + (size_t)BK_ * D_, 128, 128, nullptr, nullptr, nullptr, 0, 0, 1.f);
}

// Round 3
// 690.669 us; speedup vs baseline: 9.1889x; 3.5881x over previous
//
#include <hip/hip_runtime.h>

#define B_   8192
#define K_   5
#define D_   128
#define QD_  129
#define KD_  1285
#define SQ_  132      // padded fp32 row stride
#define BK_  40960    // B_*K_
#define QPAD 160      // bf16 k-dim padding (5 x 32)
#define VPAD 144      // bf16 out-dim padding (9 x 16)
#define KDP  1312     // KD_ padded to 41*32

typedef unsigned short u16;
typedef unsigned int   u32;
typedef __attribute__((ext_vector_type(8))) short bf8_t;
typedef __attribute__((ext_vector_type(4))) float f4_t;

#define MFMA16(a, b, c) __builtin_amdgcn_mfma_f32_16x16x32_bf16(a, b, c, 0, 0, 0)

__device__ __forceinline__ u16 f2bf(float x) {
  u32 u = __float_as_uint(x);
  u = (u + 0x7fffu + ((u >> 16) & 1u)) >> 16;
  return (u16)u;
}
__device__ __forceinline__ u32 pack2(float a, float b) {
  return (u32)f2bf(a) | ((u32)f2bf(b) << 16);
}

// ---------------------------------------------------------------------------
// One-time weight conversion fp32 -> bf16 with zero padding.
// Layout (u16 offsets within weight base):
//   wkv [288][1312] @0        rows 0-128 Wk, 129-257 Wv
//   wq  [144][160]  @377856
//   wo  [144][160]  @400896
//   w1  [144][288]  @423936
//   w2  [144][128]  @465408   (end 483840)
// ---------------------------------------------------------------------------
__global__ __launch_bounds__(256) void convw_k(
    const float* __restrict__ Wq, const float* __restrict__ Wk,
    const float* __restrict__ Wv, const float* __restrict__ Wo,
    const float* __restrict__ W1, const float* __restrict__ W2,
    u16* __restrict__ wb)
{
  int idx = blockIdx.x * 256 + threadIdx.x;
  if (idx < 377856) {
    int r = idx / KDP, c = idx - r * KDP;
    float v = 0.f;
    if (c < KD_) {
      if (r < 129) v = Wk[r * KD_ + c];
      else if (r < 258) v = Wv[(r - 129) * KD_ + c];
    }
    wb[idx] = f2bf(v);
    return;
  }
  int i2 = idx - 377856;
  if (i2 < 23040) {
    int r = i2 / 160, c = i2 - r * 160;
    wb[idx] = f2bf((r < 129 && c < 129) ? Wq[r * 129 + c] : 0.f);
    return;
  }
  i2 -= 23040;
  if (i2 < 23040) {
    int r = i2 / 160, c = i2 - r * 160;
    wb[idx] = f2bf((r < 129 && c < 129) ? Wo[r * 129 + c] : 0.f);
    return;
  }
  i2 -= 23040;
  if (i2 < 41472) {
    int r = i2 / 288, c = i2 - r * 288;
    wb[idx] = f2bf((r < 128 && c < 257) ? W1[r * 257 + c] : 0.f);
    return;
  }
  i2 -= 41472;
  if (i2 < 18432) {
    int r = i2 / 128, c = i2 - r * 128;
    wb[idx] = f2bf(r < 128 ? W2[r * 128 + c] : 0.f);
  }
}

// ---------------------------------------------------------------------------
// Dual KV projection: [kp;vp] = gather(nf) @ Wkv^T + [bk;bv]
// BM=128, BN=288, 512 thr, waves 4Mx2N (wave: 32 rows x 144 cols).
// A gathered fp32->bf16 inline (div-once-per-thread), W preconverted bf16.
// ---------------------------------------------------------------------------
template<int OM0, int OM1>
__global__ __launch_bounds__(512) void kvmm_k(
    const float* __restrict__ emb, const float* __restrict__ ef,
    const float* __restrict__ td, const u16* __restrict__ Wkv,
    const float* __restrict__ b0, void* __restrict__ out0, int ost0,
    const float* __restrict__ b1, void* __restrict__ out1, int ost1)
{
  __shared__ u16 As[128 * 40];
  __shared__ u16 Ws[288 * 40];
  const int t = threadIdx.x;
  const int n0 = blockIdx.x * 128;
  const int lane = t & 63, w = t >> 6;
  const int lrow = lane & 15, lk = lane >> 4;
  const int wr = w & 3, wc = w >> 2;
  const int cp = t & 15, rbase = t >> 4;   // staging coords (A)

  f4_t acc0[9], acc1[9];
#pragma unroll
  for (int ct = 0; ct < 9; ++ct) {
    acc0[ct] = (f4_t){0.f, 0.f, 0.f, 0.f};
    acc1[ct] = (f4_t){0.f, 0.f, 0.f, 0.f};
  }

  for (int kst = 0; kst < 41; ++kst) {
    const int c0 = kst * 32;
    __syncthreads();
    // ---- stage A: div once, 4 rows per thread ----
    {
      const int c = c0 + cp * 2;
      const int j0 = c / 257,       r0v = c - j0 * 257;
      const int j1 = (c + 1) / 257, r1v = (c + 1) - j1 * 257;
#pragma unroll
      for (int ri = 0; ri < 4; ++ri) {
        const int row = rbase + ri * 32;
        const int n = n0 + row;
        float f0 = 0.f, f1 = 0.f;
        if (j0 < 5) {
          int base = (n * 5 + j0) << 7;
          f0 = (r0v < 128) ? emb[base + r0v]
             : (r0v < 256) ? ef[base + r0v - 128] : td[n * 5 + j0];
        }
        if (j1 < 5) {
          int base = (n * 5 + j1) << 7;
          f1 = (r1v < 128) ? emb[base + r1v]
             : (r1v < 256) ? ef[base + r1v - 128] : td[n * 5 + j1];
        }
        *(u32*)&As[row * 40 + cp * 2] = pack2(f0, f1);
      }
    }
    // ---- stage W: 288 rows x 4 uint4 ----
    for (int e = t; e < 1152; e += 512) {
      int row = e >> 2, seg = e & 3;
      *(uint4*)&Ws[row * 40 + seg * 8] =
          *(const uint4*)&Wkv[(size_t)row * KDP + c0 + seg * 8];
    }
    __syncthreads();
    bf8_t af0 = *(const bf8_t*)&As[(wr * 32 +      lrow) * 40 + lk * 8];
    bf8_t af1 = *(const bf8_t*)&As[(wr * 32 + 16 + lrow) * 40 + lk * 8];
#pragma unroll
    for (int ct = 0; ct < 9; ++ct) {
      bf8_t bf = *(const bf8_t*)&Ws[(wc * 144 + ct * 16 + lrow) * 40 + lk * 8];
      acc0[ct] = MFMA16(af0, bf, acc0[ct]);
      acc1[ct] = MFMA16(af1, bf, acc1[ct]);
    }
  }

#pragma unroll
  for (int ct = 0; ct < 9; ++ct) {
    const int col = wc * 144 + ct * 16 + lrow;
#pragma unroll
    for (int rf = 0; rf < 2; ++rf) {
#pragma unroll
      for (int r = 0; r < 4; ++r) {
        const int n = n0 + wr * 32 + rf * 16 + lk * 4 + r;
        float v = (rf == 0) ? acc0[ct][r] : acc1[ct][r];
        if (col < 129) {
          v += b0[col];
          if (OM0 == 0)      ((float*)out0)[(size_t)n * ost0 + col] = v;
          else if (OM0 == 1) ((u16*)out0)[(size_t)n * ost0 + col] = f2bf(v);
          else               ((u16*)out0)[(size_t)col * ost0 + n] = f2bf(v);
        } else if (col < 258) {
          int o = col - 129;
          v += b1[o];
          if (OM1 == 0)      ((float*)out1)[(size_t)n * ost1 + o] = v;
          else if (OM1 == 1) ((u16*)out1)[(size_t)n * ost1 + o] = f2bf(v);
          else               ((u16*)out1)[(size_t)o * ost1 + n] = f2bf(v);
        }
      }
    }
  }
}

// ---------------------------------------------------------------------------
// Generic bf16 MFMA GEMM: out[n][o] = op((A[n]@Wb[o] + bias[o]) * scale)
// BM=256, N<=144, 512 thr, 8 waves x (32 rows x 144 cols). K = nK*32.
// GMB=0: A bf16 row-major (stride ast, uint4-aligned).
// GMB=1: A = [emb f32 [n][128] | td[n] (or 0) | zeros]  (q-projection input)
// OM: 0 = f32, 1 = bf16 row-major.
// ---------------------------------------------------------------------------
template<int GMB, bool RELU, int OM>
__global__ __launch_bounds__(512) void mmb_k(
    int nK, const void* __restrict__ A, int ast, const float* __restrict__ td,
    const u16* __restrict__ Wb, const float* __restrict__ bias, float scale,
    void* __restrict__ out, int ost, int N)
{
  __shared__ u16 As[256 * 40];
  __shared__ u16 Ws[144 * 40];
  const int t = threadIdx.x;
  const int n0 = blockIdx.x * 256;
  const int lane = t & 63, w = t >> 6;
  const int lrow = lane & 15, lk = lane >> 4;
  const int cp = t & 15, rbase = t >> 4;

  f4_t acc0[9], acc1[9];
#pragma unroll
  for (int ct = 0; ct < 9; ++ct) {
    acc0[ct] = (f4_t){0.f, 0.f, 0.f, 0.f};
    acc1[ct] = (f4_t){0.f, 0.f, 0.f, 0.f};
  }

  const int Kw = nK * 32;
  for (int kst = 0; kst < nK; ++kst) {
    const int c0 = kst * 32;
    __syncthreads();
    if (GMB == 0) {
      for (int e = t; e < 1024; e += 512) {
        int row = e >> 2, seg = e & 3;
        *(uint4*)&As[row * 40 + seg * 8] =
            *(const uint4*)((const u16*)A + (size_t)(n0 + row) * ast + c0 + seg * 8);
      }
    } else {
      const int c = c0 + cp * 2;
#pragma unroll
      for (int ri = 0; ri < 8; ++ri) {
        const int row = rbase + ri * 32;
        const int n = n0 + row;
        float f0 = 0.f, f1 = 0.f;
        if (c < 128)       f0 = ((const float*)A)[(n << 7) + c];
        else if (c == 128) f0 = td ? td[n] : 0.f;
        if (c + 1 < 128)       f1 = ((const float*)A)[(n << 7) + c + 1];
        else if (c + 1 == 128) f1 = td ? td[n] : 0.f;
        *(u32*)&As[row * 40 + cp * 2] = pack2(f0, f1);
      }
    }
    for (int e = t; e < 576; e += 512) {
      int row = e >> 2, seg = e & 3;
      *(uint4*)&Ws[row * 40 + seg * 8] =
          *(const uint4*)&Wb[(size_t)row * Kw + c0 + seg * 8];
    }
    __syncthreads();
    bf8_t af0 = *(const bf8_t*)&As[(w * 32 +      lrow) * 40 + lk * 8];
    bf8_t af1 = *(const bf8_t*)&As[(w * 32 + 16 + lrow) * 40 + lk * 8];
#pragma unroll
    for (int ct = 0; ct < 9; ++ct) {
      bf8_t bf = *(const bf8_t*)&Ws[(ct * 16 + lrow) * 40 + lk * 8];
      acc0[ct] = MFMA16(af0, bf, acc0[ct]);
      acc1[ct] = MFMA16(af1, bf, acc1[ct]);
    }
  }

#pragma unroll
  for (int ct = 0; ct < 9; ++ct) {
    const int col = ct * 16 + lrow;
    if (col < N) {
      const float bb = bias[col];
#pragma unroll
      for (int rf = 0; rf < 2; ++rf) {
#pragma unroll
        for (int r = 0; r < 4; ++r) {
          const int n = n0 + w * 32 + rf * 16 + lk * 4 + r;
          float v = ((rf == 0) ? acc0[ct][r] : acc1[ct][r]) + bb;
          v *= scale;
          if (RELU) v = fmaxf(v, 0.f);
          if (OM == 0) ((float*)out)[(size_t)n * ost + col] = v;
          else         ((u16*)out)[(size_t)n * ost + col] = f2bf(v);
        }
      }
    }
  }
}

// ---------------------------------------------------------------------------
// emb pack: f32 [rows][128] -> bf16 into dst cols 129..256 (stride 288)
// ---------------------------------------------------------------------------
__global__ __launch_bounds__(256) void embpack_k(
    const float* __restrict__ src, u16* __restrict__ dst, int rows)
{
  int idx = blockIdx.x * 256 + threadIdx.x;
  if (idx >= rows * 128) return;
  int n = idx >> 7, c = idx & 127;
  dst[(size_t)n * 288 + 129 + c] = f2bf(src[idx]);
}

// ---------------------------------------------------------------------------
// i=0 attention: per batch b, 5 queries x 5 keys, dim 129.
// Output bf16 [40960][160] with zero pads.
// ---------------------------------------------------------------------------
__global__ __launch_bounds__(256) void attn0_k(
    const float* __restrict__ qp, const float* __restrict__ kp,
    const float* __restrict__ vp, u16* __restrict__ o0b)
{
  __shared__ float qs[4][5][SQ_], ks[4][5][SQ_], vs[4][5][SQ_];
  __shared__ float ps[4][5][8];
  const int t = threadIdx.x;
  const int bbase = blockIdx.x * 4;
  for (int idx = t; idx < 4 * 5 * SQ_; idx += 256) {
    int bl = idx / (5 * SQ_);
    int rem = idx - bl * 5 * SQ_;
    int row = rem / SQ_;
    int d = rem - row * SQ_;
    int n = (bbase + bl) * 5 + row;
    float qv = 0.f, kv = 0.f, vv = 0.f;
    if (d < QD_) { qv = qp[n * SQ_ + d]; kv = kp[n * SQ_ + d]; vv = vp[n * SQ_ + d]; }
    qs[bl][row][d] = qv; ks[bl][row][d] = kv; vs[bl][row][d] = vv;
  }
  __syncthreads();
  const int w = t >> 6, lane = t & 63;
  if (lane < 25) {
    int qq = lane / 5, kk = lane - (lane / 5) * 5;
    float s = 0.f;
    for (int c = 0; c < QD_; ++c) s += qs[w][qq][c] * ks[w][kk][c];
    ps[w][qq][kk] = s;
  }
  __syncthreads();
  if (lane < 5) {
    float m = -1e30f;
#pragma unroll
    for (int k = 0; k < 5; ++k) m = fmaxf(m, ps[w][lane][k]);
    float l = 0.f; float e[5];
#pragma unroll
    for (int k = 0; k < 5; ++k) { e[k] = __expf(ps[w][lane][k] - m); l += e[k]; }
    float inv = 1.f / l;
#pragma unroll
    for (int k = 0; k < 5; ++k) ps[w][lane][k] = e[k] * inv;
  }
  __syncthreads();
  for (int d = lane; d < 160; d += 64) {
#pragma unroll
    for (int qq = 0; qq < 5; ++qq) {
      float o = 0.f;
      if (d < QD_) {
#pragma unroll
        for (int k = 0; k < 5; ++k) o += ps[w][qq][k] * vs[w][k][d];
      }
      o0b[(size_t)((bbase + w) * 5 + qq) * 160 + d] = f2bf(o);
    }
  }
}

// ---------------------------------------------------------------------------
// i=1 MFMA flash attention (unchanged from round 2).
// ---------------------------------------------------------------------------
#define KSS 168
#define VSS 72
#define PSS 72
#define NSPLIT 4
__global__ __launch_bounds__(256) void flashm_k(
    const u16* __restrict__ qp, const u16* __restrict__ kp,
    const u16* __restrict__ vpT, float* __restrict__ oacc,
    float* __restrict__ marr, float* __restrict__ larr)
{
  __shared__ u16 ks[64 * KSS];
  __shared__ u16 vsT[VPAD * VSS];
  __shared__ u16 ps[64 * PSS];
  const int t = threadIdx.x;
  const int split = blockIdx.x & (NSPLIT - 1);
  const int q0 = (blockIdx.x >> 2) * 64;
  const int w = t >> 6, lane = t & 63;
  const int lrow = lane & 15, lk = lane >> 4;

  bf8_t qf[5];
  {
    const u16* qrow = qp + (size_t)(q0 + w * 16 + lrow) * QPAD;
#pragma unroll
    for (int kst = 0; kst < 5; ++kst)
      qf[kst] = *(const bf8_t*)(qrow + kst * 32 + lk * 8);
  }

  f4_t acc[9];
#pragma unroll
  for (int ct = 0; ct < 9; ++ct) acc[ct] = (f4_t){0.f, 0.f, 0.f, 0.f};
  float m_[4] = {-1e30f, -1e30f, -1e30f, -1e30f};
  float l_[4] = {0.f, 0.f, 0.f, 0.f};

  const int kbase = split * (B_ / NSPLIT);
  for (int tile = 0; tile < (B_ / NSPLIT) / 64; ++tile) {
    const int k0 = kbase + tile * 64;
    __syncthreads();
    for (int e = t; e < 64 * 20; e += 256) {
      int r = e / 20, c = e - r * 20;
      *(uint4*)&ks[r * KSS + c * 8] = *(const uint4*)(kp + (size_t)(k0 + r) * QPAD + c * 8);
    }
    for (int e = t; e < VPAD * 8; e += 256) {
      int r = e >> 3, c = e & 7;
      *(uint4*)&vsT[r * VSS + c * 8] = *(const uint4*)(vpT + (size_t)r * B_ + k0 + c * 8);
    }
    __syncthreads();

    f4_t s[4];
#pragma unroll
    for (int ct = 0; ct < 4; ++ct) s[ct] = (f4_t){0.f, 0.f, 0.f, 0.f};
#pragma unroll
    for (int kst = 0; kst < 5; ++kst) {
#pragma unroll
      for (int ct = 0; ct < 4; ++ct) {
        bf8_t b = *(const bf8_t*)&ks[(ct * 16 + lrow) * KSS + kst * 32 + lk * 8];
        s[ct] = MFMA16(qf[kst], b, s[ct]);
      }
    }

    float pm[4];
#pragma unroll
    for (int r = 0; r < 4; ++r) {
      pm[r] = fmaxf(fmaxf(s[0][r], s[1][r]), fmaxf(s[2][r], s[3][r]));
#pragma unroll
      for (int mk = 1; mk <= 8; mk <<= 1) pm[r] = fmaxf(pm[r], __shfl_xor(pm[r], mk));
    }
    float cf[4], rs[4];
#pragma unroll
    for (int r = 0; r < 4; ++r) {
      float mn = fmaxf(m_[r], pm[r]);
      cf[r] = __expf(m_[r] - mn);
      m_[r] = mn;
      rs[r] = 0.f;
    }
#pragma unroll
    for (int ct = 0; ct < 4; ++ct) {
#pragma unroll
      for (int r = 0; r < 4; ++r) {
        float p = __expf(s[ct][r] - m_[r]);
        ps[(w * 16 + lk * 4 + r) * PSS + ct * 16 + lrow] = f2bf(p);
        rs[r] += p;
      }
    }
#pragma unroll
    for (int r = 0; r < 4; ++r) {
#pragma unroll
      for (int mk = 1; mk <= 8; mk <<= 1) rs[r] += __shfl_xor(rs[r], mk);
      l_[r] = l_[r] * cf[r] + rs[r];
    }
#pragma unroll
    for (int ct = 0; ct < 9; ++ct) {
#pragma unroll
      for (int r = 0; r < 4; ++r) acc[ct][r] *= cf[r];
    }
    __syncthreads();

#pragma unroll
    for (int kst = 0; kst < 2; ++kst) {
      bf8_t a = *(const bf8_t*)&ps[(w * 16 + lrow) * PSS + kst * 32 + lk * 8];
#pragma unroll
      for (int ct = 0; ct < 9; ++ct) {
        bf8_t b = *(const bf8_t*)&vsT[(ct * 16 + lrow) * VSS + kst * 32 + lk * 8];
        acc[ct] = MFMA16(a, b, acc[ct]);
      }
    }
  }

#pragma unroll
  for (int ct = 0; ct < 9; ++ct) {
    const int col = ct * 16 + lrow;
    if (col < SQ_) {
#pragma unroll
      for (int r = 0; r < 4; ++r)
        oacc[((size_t)split * B_ + q0 + w * 16 + lk * 4 + r) * SQ_ + col] = acc[ct][r];
    }
  }
  if (lrow == 0) {
#pragma unroll
    for (int r = 0; r < 4; ++r) {
      size_t i = (size_t)split * B_ + q0 + w * 16 + lk * 4 + r;
      marr[i] = m_[r];
      larr[i] = l_[r];
    }
  }
}

// ---------------------------------------------------------------------------
// combine splits -> o1b bf16 [8192][160] (pads zeroed)
// ---------------------------------------------------------------------------
__global__ __launch_bounds__(256) void combine_k(
    const float* __restrict__ oacc, const float* __restrict__ marr,
    const float* __restrict__ larr, u16* __restrict__ o1b)
{
  int idx = blockIdx.x * 256 + threadIdx.x;
  if (idx >= B_ * 160) return;
  int n = idx / 160, d = idx - n * 160;
  float v = 0.f;
  if (d < QD_) {
    float m = -1e30f;
#pragma unroll
    for (int s = 0; s < NSPLIT; ++s) m = fmaxf(m, marr[s * B_ + n]);
    float l = 0.f, o = 0.f;
#pragma unroll
    for (int s = 0; s < NSPLIT; ++s) {
      float e = __expf(marr[s * B_ + n] - m);
      l += larr[s * B_ + n] * e;
      o += oacc[((size_t)s * B_ + n) * SQ_ + d] * e;
    }
    v = o / l;
  }
  o1b[idx] = f2bf(v);
}

// ---------------------------------------------------------------------------
extern "C" void kernel_launch(void* const* d_in, const int* in_sizes, int n_in,
                              void* d_out, int out_size, void* d_ws, size_t ws_size,
                              hipStream_t stream)
{
  const float* emb0 = (const float*)d_in[0];
  const float* ef0  = (const float*)d_in[1];
  const float* td0  = (const float*)d_in[2];
  const float* emb1 = (const float*)d_in[3];
  const float* ef1  = (const float*)d_in[4];
  const float* td1  = (const float*)d_in[5];
  const float* emb2 = (const float*)d_in[6];
  const float* Wq = (const float*)d_in[7];
  const float* Wk = (const float*)d_in[9];  const float* bk = (const float*)d_in[10];
  const float* Wv = (const float*)d_in[11]; const float* bv = (const float*)d_in[12];
  const float* Wo = (const float*)d_in[13]; const float* bo = (const float*)d_in[14];
  const float* W1 = (const float*)d_in[15]; const float* b1 = (const float*)d_in[16];
  const float* W2 = (const float*)d_in[17]; const float* b2 = (const float*)d_in[18];
  const float* bq = (const float*)d_in[8];
  float* out = (float*)d_out;

  char* ws = (char*)d_ws;
  // weights (bf16)
  u16* wb   = (u16*)ws;
  u16* wkv  = wb;
  u16* wq_b = wb + 377856;
  u16* wo_b = wb + 400896;
  u16* w1_b = wb + 423936;
  u16* w2_b = wb + 465408;
  // activations
  float* kp0 = (float*)(ws + 1048576);    // [40960][132] f32
  float* vp0 = (float*)(ws + 22675456);
  float* qp0 = (float*)(ws + 44302336);
  u16*   o0b = (u16*)(ws + 65929216);     // [40960][160] bf16
  u16*   cat0= (u16*)(ws + 1048576);      // [40960][288] bf16 (overlays kp0/vp0)
  u16*   h0  = (u16*)(ws + 24641536);     // [40960][128] bf16
  // i=1 region (overlays qp0, live only after attn0)
  u16*   qp1b = (u16*)(ws + 44302336);    // [8192][160]
  u16*   kp1b = (u16*)(ws + 46923776);
  u16*   vp1T = (u16*)(ws + 49545216);    // [144][8192]
  u16*   o1b  = (u16*)(ws + 51904512);    // [8192][160]
  float* marr = (float*)(ws + 54525952);
  float* larr = (float*)(ws + 54657024);
  u16*   cat1 = (u16*)(ws + 54788096);    // [8192][288]
  u16*   h1   = (u16*)(ws + 59506688);    // [8192][128]
  float* oacc = (float*)(ws + 79036416);  // [4][8192][132]

  const float scale = 0.08804509063256238f;  // 1/sqrt(129)

  // ---- weights ----
  convw_k<<<1890, 256, 0, stream>>>(Wq, Wk, Wv, Wo, W1, W2, wb);

  // ---- i = 0 -------------------------------------------------------------
  kvmm_k<0, 0><<<BK_ / 128, 512, 0, stream>>>(
      emb0, ef0, td0, wkv, bk, kp0, SQ_, bv, vp0, SQ_);
  mmb_k<1, false, 0><<<BK_ / 256, 512, 0, stream>>>(
      5, emb1, 0, td1, wq_b, bq, scale, qp0, SQ_, QD_);
  attn0_k<<<B_ / 4, 256, 0, stream>>>(qp0, kp0, vp0, o0b);
  hipMemsetAsync(cat0, 0, 23592960, stream);
  embpack_k<<<(BK_ * 128 + 255) / 256, 256, 0, stream>>>(emb1, cat0, BK_);
  mmb_k<0, false, 1><<<BK_ / 256, 512, 0, stream>>>(
      5, o0b, 160, nullptr, wo_b, bo, 1.f, cat0, 288, QD_);
  mmb_k<0, true, 1><<<BK_ / 256, 512, 0, stream>>>(
      9, cat0, 288, nullptr, w1_b, b1, 1.f, h0, 128, 128);
  mmb_k<0, false, 0><<<BK_ / 256, 512, 0, stream>>>(
      4, h0, 128, nullptr, w2_b, b2, 1.f, out, 128, 128);

  // ---- i = 1 -------------------------------------------------------------
  hipMemsetAsync(qp1b, 0, 2621440, stream);
  hipMemsetAsync(kp1b, 0, 2621440, stream);
  hipMemsetAsync(vp1T, 0, 2359296, stream);
  kvmm_k<1, 2><<<B_ / 128, 512, 0, stream>>>(
      emb1, ef1, td1, wkv, bk, kp1b, QPAD, bv, vp1T, B_);
  mmb_k<1, false, 1><<<B_ / 256, 512, 0, stream>>>(
      5, emb2, 0, nullptr, wq_b, bq, scale, qp1b, QPAD, QD_);
  flashm_k<<<(B_ / 64) * NSPLIT, 256, 0, stream>>>(qp1b, kp1b, vp1T, oacc, marr, larr);
  combine_k<<<(B_ * 160 + 255) / 256, 256, 0, stream>>>(oacc, marr, larr, o1b);
  hipMemsetAsync(cat1, 0, 4718592, stream);
  embpack_k<<<(B_ * 128 + 255) / 256, 256, 0, stream>>>(emb2, cat1, B_);
  mmb_k<0, false, 1><<<B_ / 256, 512, 0, stream>>>(
      5, o1b, 160, nullptr, wo_b, bo, 1.f, cat1, 288, QD_);
  mmb_k<0, true, 1><<<B_ / 256, 512, 0, stream>>>(
      9, cat1, 288, nullptr, w1_b, b1, 1.f, h1, 128, 128);
  mmb_k<0, false, 0><<<B_ / 256, 512, 0, stream>>>(
      4, h1, 128, nullptr, w2_b, b2, 1.f, out + (size_t)BK_ * D_, 128, 128);
}